// Round 3
// baseline (156.332 us; speedup 1.0000x reference)
//
#include <hip/hip_runtime.h>

#define TPB 256

__device__ __forceinline__ float ex2(float x) { return __builtin_amdgcn_exp2f(x); }
__device__ __forceinline__ float frcp(float x) { return __builtin_amdgcn_rcpf(x); }

// sigmoid(x) = 1/(1+exp2(-log2e*x));  exp2 overflow -> inf -> rcp -> 0 (correct saturation)
__device__ __forceinline__ float sigm(float x) {
  return frcp(1.0f + ex2(-1.4426950408889634f * x));
}
// tanh(x) = 1 - 2/(exp2(2*log2e*x)+1)
__device__ __forceinline__ float ftanh(float x) {
  return fmaf(-2.0f, frcp(ex2(2.8853900817779268f * x) + 1.0f), 1.0f);
}

// All-scalar GRU weights (SROA-trivial; uniform loads -> SGPRs).
struct GruW {
  float w0, w1, w2, w3, w4, w5, w6, w7, w8, w9, w10, w11;   // wih[6][2]
  float u0, u1, u2, u3, u4, u5, u6, u7, u8, u9, u10, u11;   // whh[6][2]
  float br0, br1, bz0, bz1;      // bih+bhh combined for r,z gates
  float bin0, bin1, bhn0, bhn1;  // n-gate biases kept separate (r scales bhn side)
};

__device__ __forceinline__ GruW load_gru(const float* __restrict__ wih,
                                         const float* __restrict__ whh,
                                         const float* __restrict__ bih,
                                         const float* __restrict__ bhh) {
  GruW g;
  g.w0 = wih[0];  g.w1 = wih[1];  g.w2 = wih[2];  g.w3 = wih[3];
  g.w4 = wih[4];  g.w5 = wih[5];  g.w6 = wih[6];  g.w7 = wih[7];
  g.w8 = wih[8];  g.w9 = wih[9];  g.w10 = wih[10]; g.w11 = wih[11];
  g.u0 = whh[0];  g.u1 = whh[1];  g.u2 = whh[2];  g.u3 = whh[3];
  g.u4 = whh[4];  g.u5 = whh[5];  g.u6 = whh[6];  g.u7 = whh[7];
  g.u8 = whh[8];  g.u9 = whh[9];  g.u10 = whh[10]; g.u11 = whh[11];
  g.br0 = bih[0] + bhh[0]; g.br1 = bih[1] + bhh[1];
  g.bz0 = bih[2] + bhh[2]; g.bz1 = bih[3] + bhh[3];
  g.bin0 = bih[4]; g.bin1 = bih[5];
  g.bhn0 = bhh[4]; g.bhn1 = bhh[5];
  return g;
}

__device__ __forceinline__ void cell(const GruW& g, float x0, float x1,
                                     float& h0, float& h1) {
  float r0 = sigm(fmaf(g.w0, x0, fmaf(g.w1, x1, fmaf(g.u0, h0, fmaf(g.u1, h1, g.br0)))));
  float r1 = sigm(fmaf(g.w2, x0, fmaf(g.w3, x1, fmaf(g.u2, h0, fmaf(g.u3, h1, g.br1)))));
  float z0 = sigm(fmaf(g.w4, x0, fmaf(g.w5, x1, fmaf(g.u4, h0, fmaf(g.u5, h1, g.bz0)))));
  float z1 = sigm(fmaf(g.w6, x0, fmaf(g.w7, x1, fmaf(g.u6, h0, fmaf(g.u7, h1, g.bz1)))));
  float gin0 = fmaf(g.w8, x0, fmaf(g.w9, x1, g.bin0));
  float gin1 = fmaf(g.w10, x0, fmaf(g.w11, x1, g.bin1));
  float ghn0 = fmaf(g.u8, h0, fmaf(g.u9, h1, g.bhn0));
  float ghn1 = fmaf(g.u10, h0, fmaf(g.u11, h1, g.bhn1));
  float n0 = ftanh(fmaf(r0, ghn0, gin0));
  float n1 = ftanh(fmaf(r1, ghn1, gin1));
  h0 = fmaf(z0, h0 - n0, n0);
  h1 = fmaf(z1, h1 - n1, n1);
}

__global__ __launch_bounds__(TPB, 8) void rec_policy_kernel(
    const float* __restrict__ x,
    const float* __restrict__ up_wih, const float* __restrict__ up_whh,
    const float* __restrict__ up_bih, const float* __restrict__ up_bhh,
    const float* __restrict__ down_wih, const float* __restrict__ down_whh,
    const float* __restrict__ down_bih, const float* __restrict__ down_bhh,
    const float* __restrict__ obs_w, const float* __restrict__ obs_b,
    const float* __restrict__ out_w, const float* __restrict__ out_b,
    float* __restrict__ out, int B) {
  const long row = (long)blockIdx.x * TPB + threadIdx.x;
  if (row >= B) return;

  // Uniform weight loads -> s_load / SGPRs.
  const GruW up = load_gru(up_wih, up_whh, up_bih, up_bhh);
  const GruW dn = load_gru(down_wih, down_whh, down_bih, down_bhh);
  const float ow0 = obs_w[0], ow1 = obs_w[1], ow2 = obs_w[2], ow3 = obs_w[3],
              ow4 = obs_w[4], ow5 = obs_w[5], ow6 = obs_w[6], ow7 = obs_w[7],
              ow8 = obs_w[8], ow9 = obs_w[9], ow10 = obs_w[10], ow11 = obs_w[11],
              ow12 = obs_w[12], ow13 = obs_w[13];
  const float ob0 = obs_b[0], ob1 = obs_b[1];
  const float vw0 = out_w[0], vw1 = out_w[1], vb = out_b[0];

  // Direct row load: 19 adjacent dwords -> backend merges to dwordx4 (align 4 ok).
  // Wave covers a contiguous 64*76 B span; overlapping lines hit L1.
  const float* __restrict__ xp = x + row * 19;
  float xr0 = xp[0],  xr1 = xp[1],  xr2 = xp[2],  xr3 = xp[3],  xr4 = xp[4];
  float xr5 = xp[5],  xr6 = xp[6],  xr7 = xp[7],  xr8 = xp[8],  xr9 = xp[9];
  float xr10 = xp[10], xr11 = xp[11], xr12 = xp[12], xr13 = xp[13];
  float xr14 = xp[14], xr15 = xp[15], xr16 = xp[16], xr17 = xp[17], xr18 = xp[18];

  // ---- up GRU, 7 steps ----
  float h0 = 0.f, h1 = 0.f;
  float hu0, hu1, hu2, hu3, hu4, hu5, hu6, hu7, hu8, hu9, hu10, hu11, hu12, hu13;
  cell(up, xr5,  xr12, h0, h1); hu0 = h0;  hu1 = h1;
  cell(up, xr6,  xr13, h0, h1); hu2 = h0;  hu3 = h1;
  cell(up, xr7,  xr14, h0, h1); hu4 = h0;  hu5 = h1;
  cell(up, xr8,  xr15, h0, h1); hu6 = h0;  hu7 = h1;
  cell(up, xr9,  xr16, h0, h1); hu8 = h0;  hu9 = h1;
  cell(up, xr10, xr17, h0, h1); hu10 = h0; hu11 = h1;
  cell(up, xr11, xr18, h0, h1); hu12 = h0; hu13 = h1;

  // ---- obs linear ----
  float a0 = fmaf(xr0, ow0, fmaf(xr1, ow1, fmaf(xr2, ow2, fmaf(xr3, ow3,
             fmaf(xr4, ow4, fmaf(hu12, ow5, fmaf(hu13, ow6, ob0)))))));
  float a1 = fmaf(xr0, ow7, fmaf(xr1, ow8, fmaf(xr2, ow9, fmaf(xr3, ow10,
             fmaf(xr4, ow11, fmaf(hu12, ow12, fmaf(hu13, ow13, ob1)))))));
  h0 = a0; h1 = a1;

  // ---- down GRU, 7 steps + per-step output (adjacent dword stores merge) ----
  float* __restrict__ po = out + row * 7;
  float o0, o1, o2, o3, o4, o5, o6;
  cell(dn, hu0,  hu1,  h0, h1); o0 = fmaf(vw0, h0, fmaf(vw1, h1, vb));
  cell(dn, hu2,  hu3,  h0, h1); o1 = fmaf(vw0, h0, fmaf(vw1, h1, vb));
  cell(dn, hu4,  hu5,  h0, h1); o2 = fmaf(vw0, h0, fmaf(vw1, h1, vb));
  cell(dn, hu6,  hu7,  h0, h1); o3 = fmaf(vw0, h0, fmaf(vw1, h1, vb));
  cell(dn, hu8,  hu9,  h0, h1); o4 = fmaf(vw0, h0, fmaf(vw1, h1, vb));
  cell(dn, hu10, hu11, h0, h1); o5 = fmaf(vw0, h0, fmaf(vw1, h1, vb));
  cell(dn, hu12, hu13, h0, h1); o6 = fmaf(vw0, h0, fmaf(vw1, h1, vb));
  po[0] = o0; po[1] = o1; po[2] = o2; po[3] = o3;
  po[4] = o4; po[5] = o5; po[6] = o6;
}

extern "C" void kernel_launch(void* const* d_in, const int* in_sizes, int n_in,
                              void* d_out, int out_size, void* d_ws, size_t ws_size,
                              hipStream_t stream) {
  const float* x        = (const float*)d_in[0];
  const float* up_wih   = (const float*)d_in[1];
  const float* up_whh   = (const float*)d_in[2];
  const float* up_bih   = (const float*)d_in[3];
  const float* up_bhh   = (const float*)d_in[4];
  const float* down_wih = (const float*)d_in[5];
  const float* down_whh = (const float*)d_in[6];
  const float* down_bih = (const float*)d_in[7];
  const float* down_bhh = (const float*)d_in[8];
  const float* obs_w    = (const float*)d_in[9];
  const float* obs_b    = (const float*)d_in[10];
  const float* out_w    = (const float*)d_in[11];
  const float* out_b    = (const float*)d_in[12];
  float* out = (float*)d_out;

  const int B = in_sizes[0] / 19;
  const int blocks = (B + TPB - 1) / TPB;
  rec_policy_kernel<<<blocks, TPB, 0, stream>>>(
      x, up_wih, up_whh, up_bih, up_bhh, down_wih, down_whh, down_bih, down_bhh,
      obs_w, obs_b, out_w, out_b, out, B);
}